// Round 6
// baseline (496.535 us; speedup 1.0000x reference)
//
#include <hip/hip_runtime.h>
#include <math.h>

#define N_NODES 100000
#define N_EDGES 1600000
#define DF      128
#define D_HEAD  64

#define NWIN    128
#define WIN_SZ  782            // 128*782 = 100096 >= N_NODES
#define CAP     13312          // per-window pair capacity (mean 12500 + 7 sigma)
#define BCH     8192           // edges per block in bucket_kernel

typedef __attribute__((ext_vector_type(8))) short bf16x8;
typedef __attribute__((ext_vector_type(4))) float f32x4;

static __device__ __forceinline__ float mish_f(float v) {
    float e = __expf(v);
    float q = 1.0f + e;
    float p = q * q;
    float m = v * (p - 1.0f) / (p + 1.0f);
    return (v > 40.0f) ? v : m;   // guard fp32 overflow of p
}

static __device__ __forceinline__ unsigned short f2bf(float f) {
    unsigned int u = __builtin_bit_cast(unsigned int, f);
    unsigned int r = (u + 0x7fffu + ((u >> 16) & 1u)) >> 16;   // RNE
    return (unsigned short)r;
}
static __device__ __forceinline__ float bf2f(unsigned int bits16) {
    return __builtin_bit_cast(float, bits16 << 16);
}

// ---------------- cvt (x + weights -> bf16) + zero bucket counters ----------------

#define XB 12500   // (N_NODES*DF/4)/256 blocks for x
#define WB 288     // (65536+8192)/256 blocks for weights

__global__ void cvt_kernel(const float* __restrict__ x,
                           const float* __restrict__ Wl0, const float* __restrict__ Wr0,
                           const float* __restrict__ Wl1, const float* __restrict__ Wr1,
                           const float* __restrict__ Wh,
                           unsigned short* __restrict__ xb, unsigned short* __restrict__ wb,
                           int* __restrict__ bucket_cnt) {
    int b = blockIdx.x;
    if (b < XB) {
        int i = b * 256 + threadIdx.x;
        float4 v = ((const float4*)x)[i];
        ushort4 o;
        o.x = f2bf(v.x); o.y = f2bf(v.y); o.z = f2bf(v.z); o.w = f2bf(v.w);
        ((ushort4*)xb)[i] = o;
    } else if (b < XB + WB) {
        int id = (b - XB) * 256 + threadIdx.x;
        if (id < 65536) {
            int seg = id >> 14;
            int r   = id & 16383;
            const float* W = (seg == 0) ? Wl0 : (seg == 1) ? Wr0 : (seg == 2) ? Wl1 : Wr1;
            wb[id] = f2bf(W[r]);
        } else {
            wb[id] = f2bf(Wh[id - 65536]);
        }
    } else {
        if (threadIdx.x < NWIN) bucket_cnt[threadIdx.x] = 0;
    }
}

// ---------------- bucket: partition edges by dst window ----------------
// 4-way replicated LDS counters (cnt[w][set], set=tid&3 -> distinct banks)

__global__ __launch_bounds__(256) void bucket_kernel(const int* __restrict__ src,
                                                     const int* __restrict__ dst,
                                                     int* __restrict__ bucket_cnt,
                                                     unsigned int* __restrict__ pairs) {
    __shared__ int cnt[NWIN][4];
    __shared__ int cur[NWIN][4];
    int tid = threadIdx.x;
    int set = tid & 3;
    int e0  = blockIdx.x * BCH;
    for (int i = tid; i < NWIN * 4; i += 256) ((int*)cnt)[i] = 0;
    __syncthreads();
    #pragma unroll 4
    for (int i = 0; i < BCH / 256; ++i) {
        int e = e0 + tid + i * 256;
        if (e < N_EDGES) atomicAdd(&cnt[dst[e] / WIN_SZ][set], 1);
    }
    __syncthreads();
    if (tid < NWIN) {
        int c0 = cnt[tid][0], c1 = cnt[tid][1], c2 = cnt[tid][2], c3 = cnt[tid][3];
        int b = atomicAdd(&bucket_cnt[tid], c0 + c1 + c2 + c3);
        cur[tid][0] = b;
        cur[tid][1] = b + c0;
        cur[tid][2] = b + c0 + c1;
        cur[tid][3] = b + c0 + c1 + c2;
    }
    __syncthreads();
    #pragma unroll 4
    for (int i = 0; i < BCH / 256; ++i) {
        int e = e0 + tid + i * 256;
        if (e < N_EDGES) {
            int d  = dst[e];
            int s  = src[e];
            int w  = d / WIN_SZ;
            int dl = d - w * WIN_SZ;
            int idx = atomicAdd(&cur[w][set], 1);
            if (idx < CAP)
                pairs[(size_t)w * CAP + idx] = (unsigned)s | ((unsigned)dl << 17);
        }
    }
}

// ---------------- per-window CSR build: histogram + scan + scatter in LDS ----------------

__global__ __launch_bounds__(256) void build_win(const unsigned int* __restrict__ pairs,
                                                 const int* __restrict__ bucket_cnt,
                                                 int* __restrict__ rowstart,
                                                 int* __restrict__ csr) {
    __shared__ int ldeg[WIN_SZ];
    __shared__ int lcsr[CAP];
    __shared__ int wsum[4];
    __shared__ int red[4];

    int tid = threadIdx.x;
    int w   = blockIdx.x;
    int base_node = w * WIN_SZ;
    int nn = N_NODES - base_node;
    if (nn > WIN_SZ) nn = WIN_SZ;
    if (nn < 0) nn = 0;

    for (int i = tid; i < WIN_SZ; i += 256) ldeg[i] = 0;

    int val = (tid < w) ? bucket_cnt[tid] : 0;
    #pragma unroll
    for (int o = 32; o; o >>= 1) val += __shfl_xor(val, o);
    if ((tid & 63) == 0) red[tid >> 6] = val;
    int n_pairs = bucket_cnt[w];
    if (n_pairs > CAP) n_pairs = CAP;
    __syncthreads();
    int ebase = red[0] + red[1] + red[2] + red[3];

    const unsigned int* pw = pairs + (size_t)w * CAP;

    for (int i = tid; i < n_pairs; i += 256)
        atomicAdd(&ldeg[pw[i] >> 17], 1);
    __syncthreads();

    int i0 = tid * 4;
    int v[4];
    int s = 0;
    #pragma unroll
    for (int q = 0; q < 4; ++q) {
        v[q] = (i0 + q < nn) ? ldeg[i0 + q] : 0;
        s += v[q];
    }
    int lane = tid & 63, wv = tid >> 6;
    int sc = s;
    #pragma unroll
    for (int d = 1; d < 64; d <<= 1) {
        int t = __shfl_up(sc, d);
        if (lane >= d) sc += t;
    }
    if (lane == 63) wsum[wv] = sc;
    __syncthreads();
    int woff = 0;
    for (int q = 0; q < wv; ++q) woff += wsum[q];
    int run = woff + sc - s;
    #pragma unroll
    for (int q = 0; q < 4; ++q) {
        if (i0 + q < nn) {
            rowstart[base_node + i0 + q] = ebase + run;
            ldeg[i0 + q] = run;
            run += v[q];
        }
    }
    if (w == NWIN - 1 && tid == 0) rowstart[N_NODES] = N_EDGES;
    __syncthreads();

    for (int i = tid; i < n_pairs; i += 256) {
        unsigned int p = pw[i];
        int slot = atomicAdd(&ldeg[p >> 17], 1);
        lcsr[slot] = (int)(p & 0x1FFFFu);
    }
    __syncthreads();

    for (int i = tid; i < n_pairs; i += 256)
        csr[ebase + i] = lcsr[i];
}

// ---------------- fused SAGE layer: gather-mean -> MFMA(Wl) -> root MFMA(Wr) ----------------
// 64 dst rows per block, 4 waves. Wave wv owns LDS rows wv*16..+15 exclusively:
// gather writes them, A-frag reads them, root restage rewrites them -> NO barriers.
// B-frags read directly from global W (L2-resident 32KB), so LDS = 17.4KB only.

__global__ __launch_bounds__(256, 4) void fused_sage(const unsigned short* __restrict__ X,
                                                     const int* __restrict__ rowstart,
                                                     const int* __restrict__ csr,
                                                     const unsigned short* __restrict__ Wl,
                                                     const unsigned short* __restrict__ Wr,
                                                     const float* __restrict__ bias,
                                                     unsigned short* __restrict__ out) {
    constexpr int LDA = 136;
    __shared__ unsigned short As[64 * LDA];

    int tid  = threadIdx.x;
    int wv   = tid >> 6;
    int lane = tid & 63;
    int quad = lane >> 4;    // also the edge-slot in the gather
    int l16  = lane & 15;
    int m0   = blockIdx.x * 64;

    // ---- gather-mean: wave computes its 16 rows into As ----
    for (int n = 0; n < 16; ++n) {
        int node = m0 + wv * 16 + n;
        float acc[8];
        #pragma unroll
        for (int i = 0; i < 8; ++i) acc[i] = 0.f;
        int rs0 = 0, rs1 = 0;
        if (node < N_NODES) { rs0 = rowstart[node]; rs1 = rowstart[node + 1]; }
        for (int e0 = rs0; e0 < rs1; e0 += 16) {
            uint4 v[4];
            #pragma unroll
            for (int j = 0; j < 4; ++j) {
                int e = e0 + 4 * j + quad;
                uint4 t = {0u, 0u, 0u, 0u};
                if (e < rs1) t = *(const uint4*)(X + (size_t)csr[e] * DF + l16 * 8);
                v[j] = t;
            }
            #pragma unroll
            for (int j = 0; j < 4; ++j) {
                unsigned int w0[4] = {v[j].x, v[j].y, v[j].z, v[j].w};
                #pragma unroll
                for (int i = 0; i < 4; ++i) {
                    acc[2 * i]     += bf2f(w0[i] & 0xffffu);
                    acc[2 * i + 1] += bf2f(w0[i] >> 16);
                }
            }
        }
        #pragma unroll
        for (int i = 0; i < 8; ++i) {
            acc[i] += __shfl_xor(acc[i], 32);
            acc[i] += __shfl_xor(acc[i], 16);
        }
        if (quad == 0) {
            int dcnt = rs1 - rs0;
            float inv = 1.0f / (float)(dcnt > 0 ? dcnt : 1);
            unsigned int r[4];
            #pragma unroll
            for (int i = 0; i < 4; ++i) {
                unsigned int lo = f2bf(acc[2 * i] * inv);
                unsigned int hi = f2bf(acc[2 * i + 1] * inv);
                r[i] = lo | (hi << 16);
            }
            uint4 o = {r[0], r[1], r[2], r[3]};
            *(uint4*)&As[(wv * 16 + n) * LDA + l16 * 8] = o;
        }
    }

    // ---- phase 0: agg @ Wl^T (A from own LDS rows, B direct from global) ----
    f32x4 acc[8];
    #pragma unroll
    for (int n = 0; n < 8; ++n) acc[n] = (f32x4){0.f, 0.f, 0.f, 0.f};
    #pragma unroll
    for (int ks = 0; ks < 4; ++ks) {
        bf16x8 af = *(const bf16x8*)&As[(wv * 16 + l16) * LDA + ks * 32 + quad * 8];
        #pragma unroll
        for (int n = 0; n < 8; ++n) {
            bf16x8 bfr = *(const bf16x8*)&Wl[(n * 16 + l16) * 128 + ks * 32 + quad * 8];
            acc[n] = __builtin_amdgcn_mfma_f32_16x16x32_bf16(af, bfr, acc[n], 0, 0, 0);
        }
    }

    // ---- restage own 16 rows with root features (coalesced) ----
    #pragma unroll
    for (int i = 0; i < 4; ++i) {
        int o   = i * 1024 + lane * 16;   // byte offset in wave's 16x256B chunk
        int row = o >> 8;
        int col = o & 255;
        int gr  = m0 + wv * 16 + row;
        if (gr > N_NODES - 1) gr = N_NODES - 1;
        uint4 t = *(const uint4*)((const char*)X + (size_t)gr * 256 + col);
        *(uint4*)((char*)As + (size_t)(wv * 16 + row) * (LDA * 2) + col) = t;
    }

    // ---- phase 1: root @ Wr^T ----
    #pragma unroll
    for (int ks = 0; ks < 4; ++ks) {
        bf16x8 af = *(const bf16x8*)&As[(wv * 16 + l16) * LDA + ks * 32 + quad * 8];
        #pragma unroll
        for (int n = 0; n < 8; ++n) {
            bf16x8 bfr = *(const bf16x8*)&Wr[(n * 16 + l16) * 128 + ks * 32 + quad * 8];
            acc[n] = __builtin_amdgcn_mfma_f32_16x16x32_bf16(af, bfr, acc[n], 0, 0, 0);
        }
    }

    // ---- epilogue: bias + mish, bf16 store ----
    #pragma unroll
    for (int n = 0; n < 8; ++n) {
        int col = n * 16 + l16;
        float b = bias[col];
        #pragma unroll
        for (int r = 0; r < 4; ++r) {
            int row = m0 + wv * 16 + quad * 4 + r;
            if (row < N_NODES) {
                float v = mish_f(acc[n][r] + b);
                out[(size_t)row * 128 + col] = f2bf(v);
            }
        }
    }
}

// ---------------- head GEMM: out = H @ Wh^T + b (fp32 out), barrier-free ----------------

__global__ __launch_bounds__(256, 4) void head_gemm(const unsigned short* __restrict__ H,
                                                    const unsigned short* __restrict__ Wh,
                                                    const float* __restrict__ bias,
                                                    float* __restrict__ out) {
    constexpr int LDA = 136;
    __shared__ unsigned short As[64 * LDA];
    int tid  = threadIdx.x;
    int wv   = tid >> 6;
    int lane = tid & 63;
    int quad = lane >> 4;
    int l16  = lane & 15;
    int m0   = blockIdx.x * 64;

    #pragma unroll
    for (int i = 0; i < 4; ++i) {
        int o   = i * 1024 + lane * 16;
        int row = o >> 8;
        int col = o & 255;
        int gr  = m0 + wv * 16 + row;
        if (gr > N_NODES - 1) gr = N_NODES - 1;
        uint4 t = *(const uint4*)((const char*)H + (size_t)gr * 256 + col);
        *(uint4*)((char*)As + (size_t)(wv * 16 + row) * (LDA * 2) + col) = t;
    }

    f32x4 acc[4];
    #pragma unroll
    for (int n = 0; n < 4; ++n) acc[n] = (f32x4){0.f, 0.f, 0.f, 0.f};
    #pragma unroll
    for (int ks = 0; ks < 4; ++ks) {
        bf16x8 af = *(const bf16x8*)&As[(wv * 16 + l16) * LDA + ks * 32 + quad * 8];
        #pragma unroll
        for (int n = 0; n < 4; ++n) {
            bf16x8 bfr = *(const bf16x8*)&Wh[(n * 16 + l16) * 128 + ks * 32 + quad * 8];
            acc[n] = __builtin_amdgcn_mfma_f32_16x16x32_bf16(af, bfr, acc[n], 0, 0, 0);
        }
    }

    #pragma unroll
    for (int n = 0; n < 4; ++n) {
        int col = n * 16 + l16;
        float b = bias[col];
        #pragma unroll
        for (int r = 0; r < 4; ++r) {
            int row = m0 + wv * 16 + quad * 4 + r;
            if (row < N_NODES) out[(size_t)row * 64 + col] = acc[n][r] + b;
        }
    }
}

// ---------------- launch ----------------

extern "C" void kernel_launch(void* const* d_in, const int* in_sizes, int n_in,
                              void* d_out, int out_size, void* d_ws, size_t ws_size,
                              hipStream_t stream) {
    const float* x   = (const float*)d_in[0];
    const int*   ei  = (const int*)d_in[1];
    const float* Wl0 = (const float*)d_in[2];
    const float* bl0 = (const float*)d_in[3];
    const float* Wr0 = (const float*)d_in[4];
    const float* Wl1 = (const float*)d_in[5];
    const float* bl1 = (const float*)d_in[6];
    const float* Wr1 = (const float*)d_in[7];
    const float* Wh  = (const float*)d_in[8];
    const float* bh  = (const float*)d_in[9];
    float* out = (float*)d_out;

    const int* src = ei;
    const int* dst = ei + N_EDGES;

    char* ws = (char*)d_ws;
    size_t off = 0;
    auto alloc = [&](size_t bytes) -> void* {
        void* p = ws + off;
        off += (bytes + 255) & ~(size_t)255;
        return p;
    };
    int* rowstart   = (int*)alloc((N_NODES + 1) * 4);
    int* csr        = (int*)alloc(N_EDGES * 4);
    int* bucket_cnt = (int*)alloc(NWIN * 4);

    unsigned short* Wb  = (unsigned short*)alloc((size_t)(65536 + 8192) * 2);
    unsigned short* Xb  = (unsigned short*)alloc((size_t)N_NODES * DF * 2);
    unsigned short* H1b = (unsigned short*)alloc((size_t)N_NODES * DF * 2);

    unsigned short* Wlb0 = Wb;
    unsigned short* Wrb0 = Wb + 16384;
    unsigned short* Wlb1 = Wb + 32768;
    unsigned short* Wrb1 = Wb + 49152;
    unsigned short* Whb  = Wb + 65536;
    unsigned short* H2b  = Xb;                 // reuse: Xb dead after fused0 reads it
    unsigned int* pairs  = (unsigned int*)H1b; // reuse: pairs dead before fused0 writes H1b
                                               // (128 * 13312 * 4B = 6.8MB < 25.6MB)

    cvt_kernel<<<XB + WB + 1, 256, 0, stream>>>(x, Wl0, Wr0, Wl1, Wr1, Wh, Xb, Wb, bucket_cnt);

    bucket_kernel<<<(N_EDGES + BCH - 1) / BCH, 256, 0, stream>>>(src, dst, bucket_cnt, pairs);
    build_win<<<NWIN, 256, 0, stream>>>(pairs, bucket_cnt, rowstart, csr);

    const int grid = (N_NODES + 63) / 64;

    fused_sage<<<grid, 256, 0, stream>>>(Xb,  rowstart, csr, Wlb0, Wrb0, bl0, H1b);
    fused_sage<<<grid, 256, 0, stream>>>(H1b, rowstart, csr, Wlb1, Wrb1, bl1, H2b);
    head_gemm<<<grid, 256, 0, stream>>>(H2b, Whb, bh, out);
}

// Round 7
// 447.306 us; speedup vs baseline: 1.1101x; 1.1101x over previous
//
#include <hip/hip_runtime.h>
#include <math.h>

#define N_NODES 100000
#define N_EDGES 1600000
#define DF      128
#define D_HEAD  64

#define NWIN    128
#define WIN_SZ  782            // 128*782 = 100096 >= N_NODES
#define CAP     13312          // per-window pair capacity (mean 12500 + 7 sigma)
#define BCH     8192           // edges per block in bucket_kernel

typedef __attribute__((ext_vector_type(8))) short bf16x8;
typedef __attribute__((ext_vector_type(4))) float f32x4;

static __device__ __forceinline__ float mish_f(float v) {
    float e = __expf(v);
    float q = 1.0f + e;
    float p = q * q;
    float m = v * (p - 1.0f) / (p + 1.0f);
    return (v > 40.0f) ? v : m;   // guard fp32 overflow of p
}

static __device__ __forceinline__ unsigned short f2bf(float f) {
    unsigned int u = __builtin_bit_cast(unsigned int, f);
    unsigned int r = (u + 0x7fffu + ((u >> 16) & 1u)) >> 16;   // RNE
    return (unsigned short)r;
}
static __device__ __forceinline__ float bf2f(unsigned int bits16) {
    return __builtin_bit_cast(float, bits16 << 16);
}

// ---------------- cvt (x + weights -> bf16) + zero bucket counters ----------------

#define XB 12500   // (N_NODES*DF/4)/256 blocks for x
#define WB 288     // (65536+8192)/256 blocks for weights

__global__ void cvt_kernel(const float* __restrict__ x,
                           const float* __restrict__ Wl0, const float* __restrict__ Wr0,
                           const float* __restrict__ Wl1, const float* __restrict__ Wr1,
                           const float* __restrict__ Wh,
                           unsigned short* __restrict__ xb, unsigned short* __restrict__ wb,
                           int* __restrict__ bucket_cnt) {
    int b = blockIdx.x;
    if (b < XB) {
        int i = b * 256 + threadIdx.x;
        float4 v = ((const float4*)x)[i];
        ushort4 o;
        o.x = f2bf(v.x); o.y = f2bf(v.y); o.z = f2bf(v.z); o.w = f2bf(v.w);
        ((ushort4*)xb)[i] = o;
    } else if (b < XB + WB) {
        int id = (b - XB) * 256 + threadIdx.x;
        if (id < 65536) {
            int seg = id >> 14;
            int r   = id & 16383;
            const float* W = (seg == 0) ? Wl0 : (seg == 1) ? Wr0 : (seg == 2) ? Wl1 : Wr1;
            wb[id] = f2bf(W[r]);
        } else {
            wb[id] = f2bf(Wh[id - 65536]);
        }
    } else {
        if (threadIdx.x < NWIN) bucket_cnt[threadIdx.x] = 0;
    }
}

// ---------------- bucket: partition edges by dst window ----------------
// 4-way replicated LDS counters; dst cached in VGPRs across the two passes.

__global__ __launch_bounds__(256) void bucket_kernel(const int* __restrict__ src,
                                                     const int* __restrict__ dst,
                                                     int* __restrict__ bucket_cnt,
                                                     unsigned int* __restrict__ pairs) {
    __shared__ int cnt[NWIN][4];
    __shared__ int cur[NWIN][4];
    int tid = threadIdx.x;
    int set = tid & 3;
    int e0  = blockIdx.x * BCH;
    for (int i = tid; i < NWIN * 4; i += 256) ((int*)cnt)[i] = 0;
    __syncthreads();

    int dc[BCH / 256];
    #pragma unroll 4
    for (int i = 0; i < BCH / 256; ++i) {
        int e = e0 + tid + i * 256;
        int d = (e < N_EDGES) ? dst[e] : -1;
        dc[i] = d;
        if (d >= 0) atomicAdd(&cnt[d / WIN_SZ][set], 1);
    }
    __syncthreads();
    if (tid < NWIN) {
        int c0 = cnt[tid][0], c1 = cnt[tid][1], c2 = cnt[tid][2], c3 = cnt[tid][3];
        int b = atomicAdd(&bucket_cnt[tid], c0 + c1 + c2 + c3);
        cur[tid][0] = b;
        cur[tid][1] = b + c0;
        cur[tid][2] = b + c0 + c1;
        cur[tid][3] = b + c0 + c1 + c2;
    }
    __syncthreads();
    #pragma unroll 4
    for (int i = 0; i < BCH / 256; ++i) {
        int d = dc[i];
        if (d >= 0) {
            int e  = e0 + tid + i * 256;
            int s  = src[e];
            int w  = d / WIN_SZ;
            int dl = d - w * WIN_SZ;
            int idx = atomicAdd(&cur[w][set], 1);
            if (idx < CAP)
                pairs[(size_t)w * CAP + idx] = (unsigned)s | ((unsigned)dl << 17);
        }
    }
}

// ---------------- per-window CSR build: histogram + scan + scatter in LDS ----------------

__global__ __launch_bounds__(256) void build_win(const unsigned int* __restrict__ pairs,
                                                 const int* __restrict__ bucket_cnt,
                                                 int* __restrict__ rowstart,
                                                 int* __restrict__ csr) {
    __shared__ int ldeg[WIN_SZ];
    __shared__ int lcsr[CAP];
    __shared__ int wsum[4];
    __shared__ int red[4];

    int tid = threadIdx.x;
    int w   = blockIdx.x;
    int base_node = w * WIN_SZ;
    int nn = N_NODES - base_node;
    if (nn > WIN_SZ) nn = WIN_SZ;
    if (nn < 0) nn = 0;

    for (int i = tid; i < WIN_SZ; i += 256) ldeg[i] = 0;

    int val = (tid < w) ? bucket_cnt[tid] : 0;
    #pragma unroll
    for (int o = 32; o; o >>= 1) val += __shfl_xor(val, o);
    if ((tid & 63) == 0) red[tid >> 6] = val;
    int n_pairs = bucket_cnt[w];
    if (n_pairs > CAP) n_pairs = CAP;
    __syncthreads();
    int ebase = red[0] + red[1] + red[2] + red[3];

    const unsigned int* pw = pairs + (size_t)w * CAP;

    for (int i = tid; i < n_pairs; i += 256)
        atomicAdd(&ldeg[pw[i] >> 17], 1);
    __syncthreads();

    int i0 = tid * 4;
    int v[4];
    int s = 0;
    #pragma unroll
    for (int q = 0; q < 4; ++q) {
        v[q] = (i0 + q < nn) ? ldeg[i0 + q] : 0;
        s += v[q];
    }
    int lane = tid & 63, wv = tid >> 6;
    int sc = s;
    #pragma unroll
    for (int d = 1; d < 64; d <<= 1) {
        int t = __shfl_up(sc, d);
        if (lane >= d) sc += t;
    }
    if (lane == 63) wsum[wv] = sc;
    __syncthreads();
    int woff = 0;
    for (int q = 0; q < wv; ++q) woff += wsum[q];
    int run = woff + sc - s;
    #pragma unroll
    for (int q = 0; q < 4; ++q) {
        if (i0 + q < nn) {
            rowstart[base_node + i0 + q] = ebase + run;
            ldeg[i0 + q] = run;
            run += v[q];
        }
    }
    if (w == NWIN - 1 && tid == 0) rowstart[N_NODES] = N_EDGES;
    __syncthreads();

    for (int i = tid; i < n_pairs; i += 256) {
        unsigned int p = pw[i];
        int slot = atomicAdd(&ldeg[p >> 17], 1);
        lcsr[slot] = (int)(p & 0x1FFFFu);
    }
    __syncthreads();

    for (int i = tid; i < n_pairs; i += 256)
        csr[ebase + i] = lcsr[i];
}

// ---------------- mean aggregation: 4 slots x 16 lanes, 16 edges in flight ----------------

__global__ __launch_bounds__(256) void aggregate_kernel(const unsigned short* __restrict__ X,
                                                        const int* __restrict__ rowstart,
                                                        const int* __restrict__ csr,
                                                        unsigned short* __restrict__ out) {
    int wv   = threadIdx.x >> 6;
    int lane = threadIdx.x & 63;
    int node = blockIdx.x * 4 + wv;
    if (node >= N_NODES) return;
    int slot = lane >> 4;
    int l16  = lane & 15;
    int rs0 = rowstart[node];
    int rs1 = rowstart[node + 1];

    float acc[8];
    #pragma unroll
    for (int i = 0; i < 8; ++i) acc[i] = 0.f;

    for (int e0 = rs0; e0 < rs1; e0 += 16) {
        uint4 v[4];
        #pragma unroll
        for (int j = 0; j < 4; ++j) {
            int e = e0 + 4 * j + slot;
            uint4 t = {0u, 0u, 0u, 0u};
            if (e < rs1) t = *(const uint4*)(X + (size_t)csr[e] * DF + l16 * 8);
            v[j] = t;
        }
        #pragma unroll
        for (int j = 0; j < 4; ++j) {
            unsigned int w0[4] = {v[j].x, v[j].y, v[j].z, v[j].w};
            #pragma unroll
            for (int i = 0; i < 4; ++i) {
                acc[2 * i]     += bf2f(w0[i] & 0xffffu);
                acc[2 * i + 1] += bf2f(w0[i] >> 16);
            }
        }
    }

    #pragma unroll
    for (int i = 0; i < 8; ++i) {
        acc[i] += __shfl_xor(acc[i], 32);
        acc[i] += __shfl_xor(acc[i], 16);
    }

    int d = rs1 - rs0;
    float inv = 1.0f / (float)(d > 0 ? d : 1);
    if (slot == 0) {
        unsigned int r[4];
        #pragma unroll
        for (int i = 0; i < 4; ++i) {
            unsigned int lo = f2bf(acc[2 * i] * inv);
            unsigned int hi = f2bf(acc[2 * i + 1] * inv);
            r[i] = lo | (hi << 16);
        }
        uint4 o = {r[0], r[1], r[2], r[3]};
        *(uint4*)(out + (size_t)node * DF + l16 * 8) = o;
    }
}

// ---------------- LDS-free MFMA GEMM: out = act([A|H] @ [Wl^T; Wr^T] + bias) ----------------
// A-rows have zero cross-wave reuse -> load A-frags straight from global (coalesced
// 64B/row windows, L1-line reuse across ks). W (<=64KB) is L1/L2-resident -> B-frags
// straight from global. No LDS, no barriers; occupancy is VGPR-bound only.

template <int COLS, bool TWO, bool MISH, bool OUT_BF16>
__global__ __launch_bounds__(256, 4) void sage_gemm(const unsigned short* __restrict__ A,
                                                    const unsigned short* __restrict__ H,
                                                    const unsigned short* __restrict__ Wl,
                                                    const unsigned short* __restrict__ Wr,
                                                    const float* __restrict__ bias,
                                                    void* __restrict__ out) {
    constexpr int NT = COLS / 16;
    int tid  = threadIdx.x;
    int wv   = tid >> 6;
    int lane = tid & 63;
    int quad = lane >> 4;
    int l16  = lane & 15;
    int m0   = blockIdx.x * 64;

    int arow = m0 + wv * 16 + l16;
    if (arow > N_NODES - 1) arow = N_NODES - 1;   // clamp; stores guarded below

    f32x4 acc[NT];
    #pragma unroll
    for (int n = 0; n < NT; ++n) acc[n] = (f32x4){0.f, 0.f, 0.f, 0.f};

    const unsigned short* Ap = A + (size_t)arow * 128 + quad * 8;
    #pragma unroll
    for (int ks = 0; ks < 4; ++ks) {
        bf16x8 af = *(const bf16x8*)(Ap + ks * 32);
        #pragma unroll
        for (int n = 0; n < NT; ++n) {
            bf16x8 bfr = *(const bf16x8*)&Wl[(n * 16 + l16) * 128 + ks * 32 + quad * 8];
            acc[n] = __builtin_amdgcn_mfma_f32_16x16x32_bf16(af, bfr, acc[n], 0, 0, 0);
        }
    }
    if constexpr (TWO) {
        const unsigned short* Hp = H + (size_t)arow * 128 + quad * 8;
        #pragma unroll
        for (int ks = 0; ks < 4; ++ks) {
            bf16x8 af = *(const bf16x8*)(Hp + ks * 32);
            #pragma unroll
            for (int n = 0; n < NT; ++n) {
                bf16x8 bfr = *(const bf16x8*)&Wr[(n * 16 + l16) * 128 + ks * 32 + quad * 8];
                acc[n] = __builtin_amdgcn_mfma_f32_16x16x32_bf16(af, bfr, acc[n], 0, 0, 0);
            }
        }
    }

    // epilogue: C/D layout col=lane&15, row=quad*4+reg
    #pragma unroll
    for (int n = 0; n < NT; ++n) {
        int col = n * 16 + l16;
        float b = bias[col];
        #pragma unroll
        for (int r = 0; r < 4; ++r) {
            int row = m0 + wv * 16 + quad * 4 + r;
            if (row < N_NODES) {
                float v = acc[n][r] + b;
                if constexpr (MISH) v = mish_f(v);
                if constexpr (OUT_BF16)
                    ((unsigned short*)out)[(size_t)row * COLS + col] = f2bf(v);
                else
                    ((float*)out)[(size_t)row * COLS + col] = v;
            }
        }
    }
}

// ---------------- launch ----------------

extern "C" void kernel_launch(void* const* d_in, const int* in_sizes, int n_in,
                              void* d_out, int out_size, void* d_ws, size_t ws_size,
                              hipStream_t stream) {
    const float* x   = (const float*)d_in[0];
    const int*   ei  = (const int*)d_in[1];
    const float* Wl0 = (const float*)d_in[2];
    const float* bl0 = (const float*)d_in[3];
    const float* Wr0 = (const float*)d_in[4];
    const float* Wl1 = (const float*)d_in[5];
    const float* bl1 = (const float*)d_in[6];
    const float* Wr1 = (const float*)d_in[7];
    const float* Wh  = (const float*)d_in[8];
    const float* bh  = (const float*)d_in[9];
    float* out = (float*)d_out;

    const int* src = ei;
    const int* dst = ei + N_EDGES;

    char* ws = (char*)d_ws;
    size_t off = 0;
    auto alloc = [&](size_t bytes) -> void* {
        void* p = ws + off;
        off += (bytes + 255) & ~(size_t)255;
        return p;
    };
    int* rowstart   = (int*)alloc((N_NODES + 1) * 4);
    int* csr        = (int*)alloc(N_EDGES * 4);
    int* bucket_cnt = (int*)alloc(NWIN * 4);

    unsigned short* Wb  = (unsigned short*)alloc((size_t)(65536 + 8192) * 2);
    unsigned short* Xb  = (unsigned short*)alloc((size_t)N_NODES * DF * 2);
    unsigned short* Ab  = (unsigned short*)alloc((size_t)N_NODES * DF * 2);
    unsigned short* H1b = (unsigned short*)alloc((size_t)N_NODES * DF * 2);

    unsigned short* Wlb0 = Wb;
    unsigned short* Wrb0 = Wb + 16384;
    unsigned short* Wlb1 = Wb + 32768;
    unsigned short* Wrb1 = Wb + 49152;
    unsigned short* Whb  = Wb + 65536;
    unsigned short* H2b  = Xb;                 // reuse: Xb dead after gemm0 reads it
    unsigned int* pairs  = (unsigned int*)H1b; // reuse: pairs dead before gemm0 writes H1b
                                               // (128 * 13312 * 4B = 6.8MB < 25.6MB)

    cvt_kernel<<<XB + WB + 1, 256, 0, stream>>>(x, Wl0, Wr0, Wl1, Wr1, Wh, Xb, Wb, bucket_cnt);

    bucket_kernel<<<(N_EDGES + BCH - 1) / BCH, 256, 0, stream>>>(src, dst, bucket_cnt, pairs);
    build_win<<<NWIN, 256, 0, stream>>>(pairs, bucket_cnt, rowstart, csr);

    const int grid = (N_NODES + 63) / 64;

    // layer 0
    aggregate_kernel<<<N_NODES / 4, 256, 0, stream>>>(Xb, rowstart, csr, Ab);
    sage_gemm<128, true, true, true><<<grid, 256, 0, stream>>>(Ab, Xb, Wlb0, Wrb0, bl0, H1b);
    // layer 1
    aggregate_kernel<<<N_NODES / 4, 256, 0, stream>>>(H1b, rowstart, csr, Ab);
    sage_gemm<128, true, true, true><<<grid, 256, 0, stream>>>(Ab, H1b, Wlb1, Wrb1, bl1, H2b);
    // head
    sage_gemm<64, false, false, false><<<grid, 256, 0, stream>>>(H2b, nullptr, Whb, nullptr, bh, out);
}

// Round 8
// 356.459 us; speedup vs baseline: 1.3930x; 1.2549x over previous
//
#include <hip/hip_runtime.h>
#include <math.h>

#define N_NODES 100000
#define N_EDGES 1600000
#define DF      128
#define D_HEAD  64

#define NWIN    128
#define WIN_SZ  782            // 128*782 = 100096 >= N_NODES
#define CAP     13312          // per-window pair capacity (mean 12500 + 7 sigma)
#define BCH     8192           // edges per block in bucket_kernel

typedef __attribute__((ext_vector_type(8))) short bf16x8;
typedef __attribute__((ext_vector_type(4))) float f32x4;

static __device__ __forceinline__ float mish_f(float v) {
    float e = __expf(v);
    float q = 1.0f + e;
    float p = q * q;
    float m = v * (p - 1.0f) / (p + 1.0f);
    return (v > 40.0f) ? v : m;   // guard fp32 overflow of p
}

static __device__ __forceinline__ unsigned short f2bf(float f) {
    unsigned int u = __builtin_bit_cast(unsigned int, f);
    unsigned int r = (u + 0x7fffu + ((u >> 16) & 1u)) >> 16;   // RNE
    return (unsigned short)r;
}

// ---------------- cvt (x + weights -> bf16) + zero bucket counters ----------------

#define XB 12500   // (N_NODES*DF/4)/256 blocks for x
#define WB 288     // (65536+8192)/256 blocks for weights

__global__ void cvt_kernel(const float* __restrict__ x,
                           const float* __restrict__ Wl0, const float* __restrict__ Wr0,
                           const float* __restrict__ Wl1, const float* __restrict__ Wr1,
                           const float* __restrict__ Wh,
                           unsigned short* __restrict__ xb, unsigned short* __restrict__ wb,
                           int* __restrict__ bucket_cnt) {
    int b = blockIdx.x;
    if (b < XB) {
        int i = b * 256 + threadIdx.x;
        float4 v = ((const float4*)x)[i];
        ushort4 o;
        o.x = f2bf(v.x); o.y = f2bf(v.y); o.z = f2bf(v.z); o.w = f2bf(v.w);
        ((ushort4*)xb)[i] = o;
    } else if (b < XB + WB) {
        int id = (b - XB) * 256 + threadIdx.x;
        if (id < 65536) {
            int seg = id >> 14;
            int r   = id & 16383;
            const float* W = (seg == 0) ? Wl0 : (seg == 1) ? Wr0 : (seg == 2) ? Wl1 : Wr1;
            wb[id] = f2bf(W[r]);
        } else {
            wb[id] = f2bf(Wh[id - 65536]);
        }
    } else {
        if (threadIdx.x < NWIN) bucket_cnt[threadIdx.x] = 0;
    }
}

// ---------------- bucket: partition edges by dst window ----------------

__global__ __launch_bounds__(256) void bucket_kernel(const int* __restrict__ src,
                                                     const int* __restrict__ dst,
                                                     int* __restrict__ bucket_cnt,
                                                     unsigned int* __restrict__ pairs) {
    __shared__ int cnt[NWIN][4];
    __shared__ int cur[NWIN][4];
    int tid = threadIdx.x;
    int set = tid & 3;
    int e0  = blockIdx.x * BCH;
    for (int i = tid; i < NWIN * 4; i += 256) ((int*)cnt)[i] = 0;
    __syncthreads();

    int dc[BCH / 256];
    #pragma unroll 4
    for (int i = 0; i < BCH / 256; ++i) {
        int e = e0 + tid + i * 256;
        int d = (e < N_EDGES) ? dst[e] : -1;
        dc[i] = d;
        if (d >= 0) atomicAdd(&cnt[d / WIN_SZ][set], 1);
    }
    __syncthreads();
    if (tid < NWIN) {
        int c0 = cnt[tid][0], c1 = cnt[tid][1], c2 = cnt[tid][2], c3 = cnt[tid][3];
        int b = atomicAdd(&bucket_cnt[tid], c0 + c1 + c2 + c3);
        cur[tid][0] = b;
        cur[tid][1] = b + c0;
        cur[tid][2] = b + c0 + c1;
        cur[tid][3] = b + c0 + c1 + c2;
    }
    __syncthreads();
    #pragma unroll 4
    for (int i = 0; i < BCH / 256; ++i) {
        int d = dc[i];
        if (d >= 0) {
            int e  = e0 + tid + i * 256;
            int s  = src[e];
            int w  = d / WIN_SZ;
            int dl = d - w * WIN_SZ;
            int idx = atomicAdd(&cur[w][set], 1);
            if (idx < CAP)
                pairs[(size_t)w * CAP + idx] = (unsigned)s | ((unsigned)dl << 17);
        }
    }
}

// ---------------- per-window CSR build: histogram + scan + scatter in LDS ----------------

__global__ __launch_bounds__(256) void build_win(const unsigned int* __restrict__ pairs,
                                                 const int* __restrict__ bucket_cnt,
                                                 int* __restrict__ rowstart,
                                                 int* __restrict__ csr) {
    __shared__ int ldeg[WIN_SZ];
    __shared__ int lcsr[CAP];
    __shared__ int wsum[4];
    __shared__ int red[4];

    int tid = threadIdx.x;
    int w   = blockIdx.x;
    int base_node = w * WIN_SZ;
    int nn = N_NODES - base_node;
    if (nn > WIN_SZ) nn = WIN_SZ;
    if (nn < 0) nn = 0;

    for (int i = tid; i < WIN_SZ; i += 256) ldeg[i] = 0;

    int val = (tid < w) ? bucket_cnt[tid] : 0;
    #pragma unroll
    for (int o = 32; o; o >>= 1) val += __shfl_xor(val, o);
    if ((tid & 63) == 0) red[tid >> 6] = val;
    int n_pairs = bucket_cnt[w];
    if (n_pairs > CAP) n_pairs = CAP;
    __syncthreads();
    int ebase = red[0] + red[1] + red[2] + red[3];

    const unsigned int* pw = pairs + (size_t)w * CAP;

    for (int i = tid; i < n_pairs; i += 256)
        atomicAdd(&ldeg[pw[i] >> 17], 1);
    __syncthreads();

    int i0 = tid * 4;
    int v[4];
    int s = 0;
    #pragma unroll
    for (int q = 0; q < 4; ++q) {
        v[q] = (i0 + q < nn) ? ldeg[i0 + q] : 0;
        s += v[q];
    }
    int lane = tid & 63, wv = tid >> 6;
    int sc = s;
    #pragma unroll
    for (int d = 1; d < 64; d <<= 1) {
        int t = __shfl_up(sc, d);
        if (lane >= d) sc += t;
    }
    if (lane == 63) wsum[wv] = sc;
    __syncthreads();
    int woff = 0;
    for (int q = 0; q < wv; ++q) woff += wsum[q];
    int run = woff + sc - s;
    #pragma unroll
    for (int q = 0; q < 4; ++q) {
        if (i0 + q < nn) {
            rowstart[base_node + i0 + q] = ebase + run;
            ldeg[i0 + q] = run;
            run += v[q];
        }
    }
    if (w == NWIN - 1 && tid == 0) rowstart[N_NODES] = N_EDGES;
    __syncthreads();

    for (int i = tid; i < n_pairs; i += 256) {
        unsigned int p = pw[i];
        int slot = atomicAdd(&ldeg[p >> 17], 1);
        lcsr[slot] = (int)(p & 0x1FFFFu);
    }
    __syncthreads();

    for (int i = tid; i < n_pairs; i += 256)
        csr[ebase + i] = lcsr[i];
}

// ---------------- mean aggregation: 4 slots x 16 lanes, 16 edges in flight ----------------
// bf16 decode via shift/mask only (hi half of a packed pair IS the fp32 pattern).

__global__ __launch_bounds__(256) void aggregate_kernel(const unsigned short* __restrict__ X,
                                                        const int* __restrict__ rowstart,
                                                        const int* __restrict__ csr,
                                                        unsigned short* __restrict__ out) {
    int wv   = threadIdx.x >> 6;
    int lane = threadIdx.x & 63;
    int node = blockIdx.x * 4 + wv;
    if (node >= N_NODES) return;
    int slot = lane >> 4;
    int l16  = lane & 15;
    int rs0 = rowstart[node];
    int rs1 = rowstart[node + 1];

    float acc[8];
    #pragma unroll
    for (int i = 0; i < 8; ++i) acc[i] = 0.f;

    for (int e0 = rs0; e0 < rs1; e0 += 16) {
        uint4 v[4];
        #pragma unroll
        for (int j = 0; j < 4; ++j) {
            int e = e0 + 4 * j + slot;
            uint4 t = {0u, 0u, 0u, 0u};
            if (e < rs1) t = *(const uint4*)(X + (size_t)csr[e] * DF + l16 * 8);
            v[j] = t;
        }
        #pragma unroll
        for (int j = 0; j < 4; ++j) {
            unsigned int w0[4] = {v[j].x, v[j].y, v[j].z, v[j].w};
            #pragma unroll
            for (int i = 0; i < 4; ++i) {
                acc[2 * i]     += __builtin_bit_cast(float, w0[i] << 16);
                acc[2 * i + 1] += __builtin_bit_cast(float, w0[i] & 0xffff0000u);
            }
        }
    }

    #pragma unroll
    for (int i = 0; i < 8; ++i) {
        acc[i] += __shfl_xor(acc[i], 32);
        acc[i] += __shfl_xor(acc[i], 16);
    }

    int d = rs1 - rs0;
    float inv = 1.0f / (float)(d > 0 ? d : 1);
    if (slot == 0) {
        unsigned int r[4];
        #pragma unroll
        for (int i = 0; i < 4; ++i) {
            unsigned int lo = f2bf(acc[2 * i] * inv);
            unsigned int hi = f2bf(acc[2 * i + 1] * inv);
            r[i] = lo | (hi << 16);
        }
        uint4 o = {r[0], r[1], r[2], r[3]};
        *(uint4*)(out + (size_t)node * DF + l16 * 8) = o;
    }
}

// ---------------- MFMA GEMM: out = act([A|H] @ [Wl^T; Wr^T] + bias) ----------------
// Block = 128 rows (4 waves x 2 row-tiles). W staged in LDS (LDA=136, conflict-free);
// A/H frags direct from global (no cross-wave reuse; L1-reused across ks).
// ks-outer / tile-inner: each ds_read B-frag feeds 2 MFMAs.

template <int COLS, bool TWO, bool MISH, bool OUT_BF16>
__global__ __launch_bounds__(256, 3) void sage_gemm(const unsigned short* __restrict__ A,
                                                    const unsigned short* __restrict__ H,
                                                    const unsigned short* __restrict__ Wl,
                                                    const unsigned short* __restrict__ Wr,
                                                    const float* __restrict__ bias,
                                                    void* __restrict__ out) {
    constexpr int NT  = COLS / 16;
    constexpr int LDA = 136;
    __shared__ unsigned short Ws[COLS * LDA];

    int tid  = threadIdx.x;
    int wv   = tid >> 6;
    int lane = tid & 63;
    int quad = lane >> 4;
    int l16  = lane & 15;
    int m0   = blockIdx.x * 128;

    int arow0 = m0 + wv * 32 + l16;
    int arow1 = arow0 + 16;
    if (arow0 > N_NODES - 1) arow0 = N_NODES - 1;
    if (arow1 > N_NODES - 1) arow1 = N_NODES - 1;

    f32x4 acc[2][NT];
    #pragma unroll
    for (int t = 0; t < 2; ++t)
        #pragma unroll
        for (int n = 0; n < NT; ++n) acc[t][n] = (f32x4){0.f, 0.f, 0.f, 0.f};

    #pragma unroll
    for (int phase = 0; phase < (TWO ? 2 : 1); ++phase) {
        const unsigned short* Ain = phase ? H : A;
        const unsigned short* Win = phase ? Wr : Wl;
        if (phase) __syncthreads();   // all waves done reading previous Ws
        #pragma unroll
        for (int i = 0; i < COLS / 16; ++i) {
            int idx = tid + i * 256;
            int r   = idx >> 4;
            int cb  = (idx & 15) * 8;
            *(uint4*)&Ws[r * LDA + cb] = *(const uint4*)&Win[r * 128 + cb];
        }
        __syncthreads();

        const unsigned short* Ap0 = Ain + (size_t)arow0 * 128 + quad * 8;
        const unsigned short* Ap1 = Ain + (size_t)arow1 * 128 + quad * 8;
        #pragma unroll
        for (int ks = 0; ks < 4; ++ks) {
            bf16x8 af0 = *(const bf16x8*)(Ap0 + ks * 32);
            bf16x8 af1 = *(const bf16x8*)(Ap1 + ks * 32);
            #pragma unroll
            for (int n = 0; n < NT; ++n) {
                bf16x8 bfr = *(const bf16x8*)&Ws[(n * 16 + l16) * LDA + ks * 32 + quad * 8];
                acc[0][n] = __builtin_amdgcn_mfma_f32_16x16x32_bf16(af0, bfr, acc[0][n], 0, 0, 0);
                acc[1][n] = __builtin_amdgcn_mfma_f32_16x16x32_bf16(af1, bfr, acc[1][n], 0, 0, 0);
            }
        }
    }

    // epilogue: C/D layout col=lane&15, row=quad*4+reg
    #pragma unroll
    for (int t = 0; t < 2; ++t) {
        #pragma unroll
        for (int n = 0; n < NT; ++n) {
            int col = n * 16 + l16;
            float b = bias[col];
            #pragma unroll
            for (int r = 0; r < 4; ++r) {
                int row = m0 + wv * 32 + t * 16 + quad * 4 + r;
                if (row < N_NODES) {
                    float v = acc[t][n][r] + b;
                    if constexpr (MISH) v = mish_f(v);
                    if constexpr (OUT_BF16)
                        ((unsigned short*)out)[(size_t)row * COLS + col] = f2bf(v);
                    else
                        ((float*)out)[(size_t)row * COLS + col] = v;
                }
            }
        }
    }
}

// ---------------- launch ----------------

extern "C" void kernel_launch(void* const* d_in, const int* in_sizes, int n_in,
                              void* d_out, int out_size, void* d_ws, size_t ws_size,
                              hipStream_t stream) {
    const float* x   = (const float*)d_in[0];
    const int*   ei  = (const int*)d_in[1];
    const float* Wl0 = (const float*)d_in[2];
    const float* bl0 = (const float*)d_in[3];
    const float* Wr0 = (const float*)d_in[4];
    const float* Wl1 = (const float*)d_in[5];
    const float* bl1 = (const float*)d_in[6];
    const float* Wr1 = (const float*)d_in[7];
    const float* Wh  = (const float*)d_in[8];
    const float* bh  = (const float*)d_in[9];
    float* out = (float*)d_out;

    const int* src = ei;
    const int* dst = ei + N_EDGES;

    char* ws = (char*)d_ws;
    size_t off = 0;
    auto alloc = [&](size_t bytes) -> void* {
        void* p = ws + off;
        off += (bytes + 255) & ~(size_t)255;
        return p;
    };
    int* rowstart   = (int*)alloc((N_NODES + 1) * 4);
    int* csr        = (int*)alloc(N_EDGES * 4);
    int* bucket_cnt = (int*)alloc(NWIN * 4);

    unsigned short* Wb  = (unsigned short*)alloc((size_t)(65536 + 8192) * 2);
    unsigned short* Xb  = (unsigned short*)alloc((size_t)N_NODES * DF * 2);
    unsigned short* Ab  = (unsigned short*)alloc((size_t)N_NODES * DF * 2);
    unsigned short* H1b = (unsigned short*)alloc((size_t)N_NODES * DF * 2);

    unsigned short* Wlb0 = Wb;
    unsigned short* Wrb0 = Wb + 16384;
    unsigned short* Wlb1 = Wb + 32768;
    unsigned short* Wrb1 = Wb + 49152;
    unsigned short* Whb  = Wb + 65536;
    unsigned short* H2b  = Xb;                 // reuse: Xb dead after gemm0 reads it
    unsigned int* pairs  = (unsigned int*)H1b; // reuse: pairs dead before gemm0 writes H1b

    cvt_kernel<<<XB + WB + 1, 256, 0, stream>>>(x, Wl0, Wr0, Wl1, Wr1, Wh, Xb, Wb, bucket_cnt);

    bucket_kernel<<<(N_EDGES + BCH - 1) / BCH, 256, 0, stream>>>(src, dst, bucket_cnt, pairs);
    build_win<<<NWIN, 256, 0, stream>>>(pairs, bucket_cnt, rowstart, csr);

    const int grid = (N_NODES + 127) / 128;

    // layer 0
    aggregate_kernel<<<N_NODES / 4, 256, 0, stream>>>(Xb, rowstart, csr, Ab);
    sage_gemm<128, true, true, true><<<grid, 256, 0, stream>>>(Ab, Xb, Wlb0, Wrb0, bl0, H1b);
    // layer 1
    aggregate_kernel<<<N_NODES / 4, 256, 0, stream>>>(H1b, rowstart, csr, Ab);
    sage_gemm<128, true, true, true><<<grid, 256, 0, stream>>>(Ab, H1b, Wlb1, Wrb1, bl1, H2b);
    // head
    sage_gemm<64, false, false, false><<<grid, 256, 0, stream>>>(H2b, nullptr, Whb, nullptr, bh, out);
}